// Round 3
// baseline (339.616 us; speedup 1.0000x reference)
//
#include <hip/hip_runtime.h>

// spatial_encoding_block: B=65536, C=105, H=W=3
//   nearest-fill (mask from x[0,0,:,:]) -> depthwise 2x2 conv + bias
//   -> LeakyReLU(0.2) -> max over 2x2 -> + filled center -> [B,C] out.
// HBM floor: ~248 MB in + ~27.5 MB out => ~41 us at 6.7 TB/s.
// R2 probe: remove ALL block-level sync. Pre-kernel computes packed near-map
// into d_ws; main kernel uses wave-private LDS staging (no __syncthreads).

#define NC 105
#define GPB 512  // groups per block (4 waves x 128)

__global__ void se_map_kernel(const float* __restrict__ x,
                              unsigned long long* __restrict__ mapout) {
    // single thread: 9-entry nearest-fill map, 4 bits each, packed into u64
    bool mask[9];
    #pragma unroll
    for (int p = 0; p < 9; ++p) mask[p] = (x[p] == 0.0f);
    unsigned long long pk = 0;
    #pragma unroll
    for (int p = 0; p < 9; ++p) {
        int np = p;
        if (mask[p]) {
            int best = 0x7fffffff, bq = 0;
            const int pi = p / 3, pj = p % 3;
            for (int q = 0; q < 9; ++q) {
                if (mask[q]) continue;               // exclude zero pixels as sources
                const int qi = q / 3, qj = q % 3;
                const int d = (pi - qi) * (pi - qi) + (pj - qj) * (pj - qj);
                if (d < best) { best = d; bq = q; }  // ties -> lowest flat index
            }
            np = bq;
        }
        pk |= (unsigned long long)np << (4 * p);
    }
    *mapout = pk;
}

__global__ __launch_bounds__(256) void se_kernel(const float* __restrict__ x,
                                                 const float* __restrict__ w,
                                                 const float* __restrict__ b,
                                                 const unsigned long long* __restrict__ mapp,
                                                 float* __restrict__ out) {
    __shared__ float sx[GPB * 9];                    // 18432 B, partitioned per wave

    const int tid  = threadIdx.x;
    const int lane = tid & 63;
    const int wv   = tid >> 6;                       // wave id 0..3
    const int gbase = blockIdx.x * GPB;

    const float4* x4 = (const float4*)(x + (long long)gbase * 9);  // 18432B-aligned base
    float4* sx4 = (float4*)sx;

    // ---- wave-private staging: wave wv owns f4 range [wv*288, wv*288+288) ----
    const int fb = wv * 288;
    sx4[fb + lane]       = x4[fb + lane];
    sx4[fb + lane + 64]  = x4[fb + lane + 64];
    sx4[fb + lane + 128] = x4[fb + lane + 128];
    sx4[fb + lane + 192] = x4[fb + lane + 192];
    if (lane < 32) sx4[fb + lane + 256] = x4[fb + lane + 256];
    // no __syncthreads: each wave reads only its own slice; compiler's
    // lgkmcnt wait on this wave's own DS ops orders write->read.

    // wave-uniform scalar load of the packed map
    const unsigned long long pk = *mapp;
    int nr[9];
    #pragma unroll
    for (int p = 0; p < 9; ++p) nr[p] = (int)((pk >> (4 * p)) & 15);

    const float4* w4 = (const float4*)w;

    #pragma unroll
    for (int half = 0; half < 2; ++half) {
        const int gl   = wv * 128 + half * 64 + lane;  // local group
        const int gidx = gbase + gl;                   // = b*105 + c
        const int c    = gidx % NC;

        // LDS gather: lane stride 9 dwords (odd) -> 2 lanes/bank, free
        const float* a = &sx[gl * 9];
        float v[9];
        #pragma unroll
        for (int p = 0; p < 9; ++p) v[p] = a[nr[p]];

        const float4 wc = w4[c];
        const float bias = b[c];

        float y00 = fmaf(v[0], wc.x, fmaf(v[1], wc.y, fmaf(v[3], wc.z, v[4] * wc.w))) + bias;
        float y01 = fmaf(v[1], wc.x, fmaf(v[2], wc.y, fmaf(v[4], wc.z, v[5] * wc.w))) + bias;
        float y10 = fmaf(v[3], wc.x, fmaf(v[4], wc.y, fmaf(v[6], wc.z, v[7] * wc.w))) + bias;
        float y11 = fmaf(v[4], wc.x, fmaf(v[5], wc.y, fmaf(v[7], wc.z, v[8] * wc.w))) + bias;

        y00 = (y00 > 0.0f) ? y00 : 0.2f * y00;
        y01 = (y01 > 0.0f) ? y01 : 0.2f * y01;
        y10 = (y10 > 0.0f) ? y10 : 0.2f * y10;
        y11 = (y11 > 0.0f) ? y11 : 0.2f * y11;

        const float m = fmaxf(fmaxf(y00, y01), fmaxf(y10, y11));
        out[gidx] = m + v[4];                          // + aug[:,:,1,1]
    }
}

extern "C" void kernel_launch(void* const* d_in, const int* in_sizes, int n_in,
                              void* d_out, int out_size, void* d_ws, size_t ws_size,
                              hipStream_t stream) {
    const float* x = (const float*)d_in[0];
    const float* w = (const float*)d_in[1];
    const float* b = (const float*)d_in[2];
    float* out = (float*)d_out;
    unsigned long long* map = (unsigned long long*)d_ws;

    const int n_groups = in_sizes[0] / 9;   // B*C = 6,881,280
    const int grid = n_groups / GPB;        // 13440 exactly

    se_map_kernel<<<1, 1, 0, stream>>>(x, map);
    se_kernel<<<grid, 256, 0, stream>>>(x, w, b, map, out);
}